// Round 4
// baseline (170.380 us; speedup 1.0000x reference)
//
#include <hip/hip_runtime.h>
#include <hip/hip_bf16.h>
#include <stdint.h>

#define MDIM 16384   // B*S = 4*4096
#define NDIM 2048    // MAX_OUT
#define KDIM 2048    // MAX_IN

typedef __attribute__((ext_vector_type(4))) float f32x4;
typedef __attribute__((ext_vector_type(8))) short s16x8;

__device__ __forceinline__ void gload_lds16(const __hip_bfloat16* g, void* l) {
    __builtin_amdgcn_global_load_lds(
        (const __attribute__((address_space(1))) void*)g,
        (__attribute__((address_space(3))) void*)l,
        16, 0, 0);
}

// ---------------- prep kernels (unchanged, near-BW) ----------------

__global__ __launch_bounds__(256) void prep_x(
    const float* __restrict__ x, const float* __restrict__ weights,
    const float* __restrict__ a_scales, __hip_bfloat16* __restrict__ xq)
{
    float A0 = 0.f, A1 = 0.f;
    #pragma unroll
    for (int k = 0; k < 16; ++k) {
        float w = weights[k];
        if (((k >> 1) & 1) == 0) A0 += w; else A1 += w;
    }
    const float s0 = a_scales[0], s1 = a_scales[1];
    const float r0 = 1.f / s0, r1 = 1.f / s1;

    size_t idx = ((size_t)blockIdx.x * 256 + threadIdx.x) * 8;
    const f32x4* xv = (const f32x4*)(x + idx);
    f32x4 v0 = xv[0], v1 = xv[1];
    float vals[8] = {v0.x, v0.y, v0.z, v0.w, v1.x, v1.y, v1.z, v1.w};

    union { s16x8 v; __hip_bfloat16 h[8]; } u;
    #pragma unroll
    for (int j = 0; j < 8; ++j) {
        float q0 = rintf(fminf(fmaxf(vals[j] * r0, -8.f),   7.f)) * s0;
        float q1 = rintf(fminf(fmaxf(vals[j] * r1, -128.f), 127.f)) * s1;
        u.h[j] = __float2bfloat16(A0 * q0 + A1 * q1);
    }
    *(s16x8*)(xq + idx) = u.v;
}

__global__ __launch_bounds__(256) void prep_w(
    const float* __restrict__ W, const float* __restrict__ weights,
    const float* __restrict__ w_scales, __hip_bfloat16* __restrict__ wq)
{
    float c00 = weights[0] + weights[2]  + weights[4]  + weights[6];
    float c01 = weights[1] + weights[3]  + weights[5]  + weights[7];
    float c10 = weights[8] + weights[10] + weights[12] + weights[14];
    float c11 = weights[9] + weights[11] + weights[13] + weights[15];

    const float s0 = w_scales[0], s1 = w_scales[1];
    const float r0 = 1.f / s0, r1 = 1.f / s1;

    size_t idx = ((size_t)blockIdx.x * 256 + threadIdx.x) * 8;
    const int o = (int)(idx >> 11);
    const int c = (int)(idx & 2047);
    const bool inner = (o < 1024) && (c < 1024);
    const float k0 = inner ? (c00 + c10) : c10;
    const float k1 = inner ? (c01 + c11) : c11;

    const f32x4* wv = (const f32x4*)(W + idx);
    f32x4 v0 = wv[0], v1 = wv[1];
    float vals[8] = {v0.x, v0.y, v0.z, v0.w, v1.x, v1.y, v1.z, v1.w};

    union { s16x8 v; __hip_bfloat16 h[8]; } u;
    #pragma unroll
    for (int j = 0; j < 8; ++j) {
        float q0 = rintf(fminf(fmaxf(vals[j] * r0, -8.f),   7.f)) * s0;
        float q1 = rintf(fminf(fmaxf(vals[j] * r1, -128.f), 127.f)) * s1;
        u.h[j] = __float2bfloat16(k0 * q0 + k1 * q1);
    }
    *(s16x8*)(wq + idx) = u.v;
}

__global__ __launch_bounds__(256) void prep_b(
    const float* __restrict__ b, const float* __restrict__ weights,
    float* __restrict__ bm)
{
    int o = blockIdx.x * 256 + threadIdx.x;
    if (o >= NDIM) return;
    float S1 = 0.f, S0 = 0.f;
    #pragma unroll
    for (int k = 0; k < 8; ++k)  S0 += weights[k];
    #pragma unroll
    for (int k = 8; k < 16; ++k) S1 += weights[k];
    bm[o] = b[o] * ((o < 1024) ? (S0 + S1) : S1);
}

// ---------------- GEMM: 256x256 tile, 8 waves, 4-deep K-chunk ring ----------
// Ring of 4 LDS slots (32 KB each: A 16K + B 16K, 256 rows x 32 k, swizzled).
// Step c: [barrier] [gloads c+3] [ds_read frags c+1] [lgkmcnt(12)] [32 MFMA]
// [vmcnt(4)]. One barrier/step; loads stay 3 chunks in flight; lgkm gate waits
// only the previous step's reads (typically satisfied).

#define BM 256
#define BN 256
#define NCH 64           // K chunks of 32
#define SLOTB 32768      // bytes per ring slot (A 16384 + B 16384)

#define MFMA(a, b, c) __builtin_amdgcn_mfma_f32_16x16x32_bf16((a), (b), (c), 0, 0, 0)

// afU/bfU: fragments of chunk c (ready). afL/bfL: loaded with chunk c+1.
// S1 = (c+1)&3 (read slot), S3 = (c+3)&3 (stage slot).
#define STEP(afU, bfU, afL, bfL, S1, S3)                                     \
  {                                                                          \
    __builtin_amdgcn_s_barrier();                                            \
    const __hip_bfloat16* koff_A0 = As0 + kg * 32;                           \
    const __hip_bfloat16* koff_A1 = As1 + kg * 32;                           \
    const __hip_bfloat16* koff_B0 = Bs0 + kg * 32;                           \
    const __hip_bfloat16* koff_B1 = Bs1 + kg * 32;                           \
    gload_lds16(koff_A0, lds + (S3) * SLOTB + ldoff);                        \
    gload_lds16(koff_A1, lds + (S3) * SLOTB +  8192 + ldoff);                \
    gload_lds16(koff_B0, lds + (S3) * SLOTB + 16384 + ldoff);                \
    gload_lds16(koff_B1, lds + (S3) * SLOTB + 24576 + ldoff);                \
    kg = (kg + 1) & (NCH - 1);                                               \
    {                                                                        \
      const char* a_ = lds + (S1) * SLOTB;                                   \
      const char* b_ = lds + (S1) * SLOTB + 16384;                           \
      _Pragma("unroll")                                                      \
      for (int m_ = 0; m_ < 8; ++m_)                                         \
        afL[m_] = *(const s16x8*)(a_ + aoff + m_ * 1024);                    \
      _Pragma("unroll")                                                      \
      for (int n_ = 0; n_ < 4; ++n_)                                         \
        bfL[n_] = *(const s16x8*)(b_ + boff + n_ * 1024);                    \
    }                                                                        \
    asm volatile("s_waitcnt lgkmcnt(12)" ::: "memory");                      \
    __builtin_amdgcn_sched_barrier(0);                                       \
    __builtin_amdgcn_s_setprio(1);                                           \
    _Pragma("unroll")                                                        \
    for (int m_ = 0; m_ < 8; ++m_) {                                         \
      acc[m_][0] = MFMA(afU[m_], bfU[0], acc[m_][0]);                        \
      acc[m_][1] = MFMA(afU[m_], bfU[1], acc[m_][1]);                        \
      acc[m_][2] = MFMA(afU[m_], bfU[2], acc[m_][2]);                        \
      acc[m_][3] = MFMA(afU[m_], bfU[3], acc[m_][3]);                        \
    }                                                                        \
    __builtin_amdgcn_s_setprio(0);                                           \
    asm volatile("s_waitcnt vmcnt(4)" ::: "memory");                         \
  }

__global__ __launch_bounds__(512, 2) void gemm256(
    const __hip_bfloat16* __restrict__ A,
    const __hip_bfloat16* __restrict__ B,
    const float* __restrict__ bias,
    float* __restrict__ C)
{
    __shared__ char lds[4 * SLOTB];   // 128 KiB

    const int tid  = threadIdx.x;
    const int lane = tid & 63;
    const int wid  = tid >> 6;    // 0..7
    const int wm   = wid >> 2;    // 0..1  (M half)
    const int wn   = wid & 3;     // 0..3  (N quarter)

    // T1 mapping: XCD = bid % 8 owns ONE column panel -> B (1 MB) L2-resident.
    const int bid  = blockIdx.x;
    const int brow = (bid >> 3) * BM;
    const int bcol = (bid & 7) * BN;

    // ---- staging: linear LDS dest, pre-swizzled global source (T2) ----
    // thread t writes 16B at slot-offset t*16 (row t>>2, phys chunk t&3);
    // logical k-chunk = (t&3) ^ ((t>>3)&3).
    const int csw = (tid & 3) ^ ((tid >> 3) & 3);
    const __hip_bfloat16* As0 = A + (size_t)(brow + (tid >> 2)) * KDIM + csw * 8;
    const __hip_bfloat16* As1 = As0 + (size_t)128 * KDIM;
    const __hip_bfloat16* Bs0 = B + (size_t)(bcol + (tid >> 2)) * KDIM + csw * 8;
    const __hip_bfloat16* Bs1 = Bs0 + (size_t)128 * KDIM;
    const int ldoff = tid * 16;

    // ---- fragment-read constants (swizzle inverse; lane-constant XOR) ----
    const int fr  = lane & 15;
    const int l16 = lane >> 4;
    const int xr  = (l16 ^ ((fr >> 1) & 3)) * 16;
    const int aoff = (wm * 128 + fr) * 64 + xr;
    const int boff = (wn * 64  + fr) * 64 + xr;

    f32x4 acc[8][4];
    #pragma unroll
    for (int m = 0; m < 8; ++m)
        #pragma unroll
        for (int n = 0; n < 4; ++n)
            acc[m][n] = (f32x4){0.f, 0.f, 0.f, 0.f};

    s16x8 af0[8], bf0[4], af1[8], bf1[4];
    int kg = 0;

    // ---- prologue: stage chunks 0,1,2; wait 0,1; read frags(0) ----
    #pragma unroll
    for (int q = 0; q < 3; ++q) {
        gload_lds16(As0 + q * 32, lds + q * SLOTB + ldoff);
        gload_lds16(As1 + q * 32, lds + q * SLOTB +  8192 + ldoff);
        gload_lds16(Bs0 + q * 32, lds + q * SLOTB + 16384 + ldoff);
        gload_lds16(Bs1 + q * 32, lds + q * SLOTB + 24576 + ldoff);
    }
    kg = 3;
    asm volatile("s_waitcnt vmcnt(4)" ::: "memory");  // chunks 0,1 landed
    __builtin_amdgcn_s_barrier();                     // visible to all waves
    #pragma unroll
    for (int m = 0; m < 8; ++m)
        af0[m] = *(const s16x8*)(lds + aoff + m * 1024);
    #pragma unroll
    for (int n = 0; n < 4; ++n)
        bf0[n] = *(const s16x8*)(lds + 16384 + boff + n * 1024);

    #pragma unroll 1
    for (int it = 0; it < NCH / 4; ++it) {
        STEP(af0, bf0, af1, bf1, 1, 3);   // chunk 4it
        STEP(af1, bf1, af0, bf0, 2, 0);   // chunk 4it+1
        STEP(af0, bf0, af1, bf1, 3, 1);   // chunk 4it+2
        STEP(af1, bf1, af0, bf0, 0, 2);   // chunk 4it+3
    }
    asm volatile("s_waitcnt vmcnt(0) lgkmcnt(0)" ::: "memory");

    // ---- epilogue: C/D layout col = lane&15, row = (lane>>4)*4 + j ----
    const int ccol0 = bcol + wn * 64 + fr;
    const int crow0 = brow + wm * 128 + l16 * 4;
    float bv[4];
    #pragma unroll
    for (int n = 0; n < 4; ++n) bv[n] = bias[ccol0 + n * 16];

    #pragma unroll
    for (int m = 0; m < 8; ++m) {
        #pragma unroll
        for (int j = 0; j < 4; ++j) {
            float* Crow = C + (size_t)(crow0 + m * 16 + j) * NDIM;
            #pragma unroll
            for (int n = 0; n < 4; ++n)
                Crow[ccol0 + n * 16] = acc[m][n][j] + bv[n];
        }
    }
}

// ---------------- launcher ----------------

extern "C" void kernel_launch(void* const* d_in, const int* in_sizes, int n_in,
                              void* d_out, int out_size, void* d_ws, size_t ws_size,
                              hipStream_t stream) {
    const float* x        = (const float*)d_in[0];  // [4,4096,2048]
    const float* weights  = (const float*)d_in[1];  // [16]
    const float* W        = (const float*)d_in[2];  // [2048,2048]
    const float* b        = (const float*)d_in[3];  // [2048]
    const float* a_scales = (const float*)d_in[4];  // [2]
    const float* w_scales = (const float*)d_in[5];  // [2]
    float* out = (float*)d_out;

    __hip_bfloat16* xq = (__hip_bfloat16*)d_ws;                            // 67108864 B
    __hip_bfloat16* wq = (__hip_bfloat16*)((char*)d_ws + 67108864);        //  8388608 B
    float*          bm = (float*)((char*)d_ws + 67108864 + 8388608);       //     8192 B

    prep_w<<<dim3((NDIM * KDIM) / (256 * 8)), dim3(256), 0, stream>>>(W, weights, w_scales, wq);
    prep_b<<<dim3(NDIM / 256), dim3(256), 0, stream>>>(b, weights, bm);
    prep_x<<<dim3(((size_t)MDIM * KDIM) / (256 * 8)), dim3(256), 0, stream>>>(x, weights, a_scales, xq);
    gemm256<<<dim3((MDIM / BM) * (NDIM / BN)), dim3(512), 0, stream>>>(xq, wq, bm, out);
}

// Round 5
// 161.282 us; speedup vs baseline: 1.0564x; 1.0564x over previous
//
#include <hip/hip_runtime.h>
#include <hip/hip_bf16.h>
#include <stdint.h>

#define MDIM 16384   // B*S = 4*4096
#define NDIM 2048    // MAX_OUT
#define KDIM 2048    // MAX_IN

typedef __attribute__((ext_vector_type(4))) float f32x4;
typedef __attribute__((ext_vector_type(8))) short s16x8;

__device__ __forceinline__ void gload_lds16(const __hip_bfloat16* g, void* l) {
    __builtin_amdgcn_global_load_lds(
        (const __attribute__((address_space(1))) void*)g,
        (__attribute__((address_space(3))) void*)l,
        16, 0, 0);
}

// ---------------- prep kernels (unchanged, near-BW) ----------------

__global__ __launch_bounds__(256) void prep_x(
    const float* __restrict__ x, const float* __restrict__ weights,
    const float* __restrict__ a_scales, __hip_bfloat16* __restrict__ xq)
{
    float A0 = 0.f, A1 = 0.f;
    #pragma unroll
    for (int k = 0; k < 16; ++k) {
        float w = weights[k];
        if (((k >> 1) & 1) == 0) A0 += w; else A1 += w;
    }
    const float s0 = a_scales[0], s1 = a_scales[1];
    const float r0 = 1.f / s0, r1 = 1.f / s1;

    size_t idx = ((size_t)blockIdx.x * 256 + threadIdx.x) * 8;
    const f32x4* xv = (const f32x4*)(x + idx);
    f32x4 v0 = xv[0], v1 = xv[1];
    float vals[8] = {v0.x, v0.y, v0.z, v0.w, v1.x, v1.y, v1.z, v1.w};

    union { s16x8 v; __hip_bfloat16 h[8]; } u;
    #pragma unroll
    for (int j = 0; j < 8; ++j) {
        float q0 = rintf(fminf(fmaxf(vals[j] * r0, -8.f),   7.f)) * s0;
        float q1 = rintf(fminf(fmaxf(vals[j] * r1, -128.f), 127.f)) * s1;
        u.h[j] = __float2bfloat16(A0 * q0 + A1 * q1);
    }
    *(s16x8*)(xq + idx) = u.v;
}

__global__ __launch_bounds__(256) void prep_w(
    const float* __restrict__ W, const float* __restrict__ weights,
    const float* __restrict__ w_scales, __hip_bfloat16* __restrict__ wq)
{
    float c00 = weights[0] + weights[2]  + weights[4]  + weights[6];
    float c01 = weights[1] + weights[3]  + weights[5]  + weights[7];
    float c10 = weights[8] + weights[10] + weights[12] + weights[14];
    float c11 = weights[9] + weights[11] + weights[13] + weights[15];

    const float s0 = w_scales[0], s1 = w_scales[1];
    const float r0 = 1.f / s0, r1 = 1.f / s1;

    size_t idx = ((size_t)blockIdx.x * 256 + threadIdx.x) * 8;
    const int o = (int)(idx >> 11);
    const int c = (int)(idx & 2047);
    const bool inner = (o < 1024) && (c < 1024);
    const float k0 = inner ? (c00 + c10) : c10;
    const float k1 = inner ? (c01 + c11) : c11;

    const f32x4* wv = (const f32x4*)(W + idx);
    f32x4 v0 = wv[0], v1 = wv[1];
    float vals[8] = {v0.x, v0.y, v0.z, v0.w, v1.x, v1.y, v1.z, v1.w};

    union { s16x8 v; __hip_bfloat16 h[8]; } u;
    #pragma unroll
    for (int j = 0; j < 8; ++j) {
        float q0 = rintf(fminf(fmaxf(vals[j] * r0, -8.f),   7.f)) * s0;
        float q1 = rintf(fminf(fmaxf(vals[j] * r1, -128.f), 127.f)) * s1;
        u.h[j] = __float2bfloat16(k0 * q0 + k1 * q1);
    }
    *(s16x8*)(wq + idx) = u.v;
}

__global__ __launch_bounds__(256) void prep_b(
    const float* __restrict__ b, const float* __restrict__ weights,
    float* __restrict__ bm)
{
    int o = blockIdx.x * 256 + threadIdx.x;
    if (o >= NDIM) return;
    float S1 = 0.f, S0 = 0.f;
    #pragma unroll
    for (int k = 0; k < 8; ++k)  S0 += weights[k];
    #pragma unroll
    for (int k = 8; k < 16; ++k) S1 += weights[k];
    bm[o] = b[o] * ((o < 1024) ? (S0 + S1) : S1);
}

// ---------------- GEMM: 256x256 tile, 8 waves, 4-deep K-chunk ring,
// fine interleave: [gloadA][8 ds_read][lgkm(8)][16 MFMA][gloadB][4 ds_read]
// [16 MFMA][vmcnt(4)][barrier]. Derived counted waits; 1 barrier/step. ----

#define BM 256
#define BN 256
#define NCH 64           // K chunks of 32
#define SLOTB 32768      // bytes per ring slot (A 16384 + B 16384)

#define MFMA(a, b, c) __builtin_amdgcn_mfma_f32_16x16x32_bf16((a), (b), (c), 0, 0, 0)

// afU/bfU: fragments of chunk c (gated ready here). afL/bfL: loaded with
// chunk c+1's frags. S1 = (c+1)&3 read slot, S3 = (c+3)&3 stage slot.
// Queue invariant at gate: [af(c)x8, bf(c)x4, af(c+1)x8] -> lgkmcnt(8)
// drains af(c)+bf(c), leaves the 8 fresh reads in flight under the MFMAs.
#define STEP(afU, bfU, afL, bfL, S1, S3)                                     \
  {                                                                          \
    gload_lds16(As0 + kg * 32, lds + (S3) * SLOTB + ldoff);                  \
    gload_lds16(As1 + kg * 32, lds + (S3) * SLOTB +  8192 + ldoff);          \
    _Pragma("unroll")                                                        \
    for (int m_ = 0; m_ < 8; ++m_)                                           \
      afL[m_] = *(const s16x8*)(lds + (S1) * SLOTB + aoff + m_ * 1024);      \
    asm volatile("s_waitcnt lgkmcnt(8)" ::: "memory");                       \
    __builtin_amdgcn_sched_barrier(0);                                       \
    __builtin_amdgcn_s_setprio(1);                                           \
    _Pragma("unroll")                                                        \
    for (int m_ = 0; m_ < 8; ++m_) {                                         \
      acc[m_][0] = MFMA(afU[m_], bfU[0], acc[m_][0]);                        \
      acc[m_][1] = MFMA(afU[m_], bfU[1], acc[m_][1]);                        \
    }                                                                        \
    __builtin_amdgcn_s_setprio(0);                                           \
    gload_lds16(Bs0 + kg * 32, lds + (S3) * SLOTB + 16384 + ldoff);          \
    gload_lds16(Bs1 + kg * 32, lds + (S3) * SLOTB + 24576 + ldoff);          \
    _Pragma("unroll")                                                        \
    for (int n_ = 0; n_ < 4; ++n_)                                           \
      bfL[n_] = *(const s16x8*)(lds + (S1) * SLOTB + 16384 + boff + n_ * 1024); \
    __builtin_amdgcn_s_setprio(1);                                           \
    _Pragma("unroll")                                                        \
    for (int m_ = 0; m_ < 8; ++m_) {                                         \
      acc[m_][2] = MFMA(afU[m_], bfU[2], acc[m_][2]);                        \
      acc[m_][3] = MFMA(afU[m_], bfU[3], acc[m_][3]);                        \
    }                                                                        \
    __builtin_amdgcn_s_setprio(0);                                           \
    kg = (kg + 1) & (NCH - 1);                                               \
    asm volatile("s_waitcnt vmcnt(4)" ::: "memory");                         \
    __builtin_amdgcn_s_barrier();                                            \
  }

__global__ __launch_bounds__(512, 2) void gemm256(
    const __hip_bfloat16* __restrict__ A,
    const __hip_bfloat16* __restrict__ B,
    const float* __restrict__ bias,
    float* __restrict__ C)
{
    __shared__ char lds[4 * SLOTB];   // 128 KiB

    const int tid  = threadIdx.x;
    const int lane = tid & 63;
    const int wid  = tid >> 6;    // 0..7
    const int wm   = wid >> 2;    // 0..1  (M half)
    const int wn   = wid & 3;     // 0..3  (N quarter)

    // T1 (R3 mapping, measured FETCH ~101 MB): XCD = bid%8 owns 8 row-panels
    // x all 8 cols -> A panel L2-resident, B cycles 8MB (L3-hot).
    const int bid  = blockIdx.x;
    const int swz  = (bid & 7) * 64 + (bid >> 3);
    const int brow = (swz >> 3) * BM;
    const int bcol = (swz & 7) * BN;

    // ---- staging: linear LDS dest, pre-swizzled global source (T2) ----
    // thread t writes 16B at slot-offset t*16 (row t>>2, phys chunk t&3);
    // logical k-chunk = (t&3) ^ ((t>>3)&3).  (measured: 0 bank conflicts)
    const int csw = (tid & 3) ^ ((tid >> 3) & 3);
    const __hip_bfloat16* As0 = A + (size_t)(brow + (tid >> 2)) * KDIM + csw * 8;
    const __hip_bfloat16* As1 = As0 + (size_t)128 * KDIM;
    const __hip_bfloat16* Bs0 = B + (size_t)(bcol + (tid >> 2)) * KDIM + csw * 8;
    const __hip_bfloat16* Bs1 = Bs0 + (size_t)128 * KDIM;
    const int ldoff = tid * 16;

    // ---- fragment-read constants (swizzle inverse; lane-constant XOR) ----
    const int fr  = lane & 15;
    const int l16 = lane >> 4;
    const int xr  = (l16 ^ ((fr >> 1) & 3)) * 16;
    const int aoff = (wm * 128 + fr) * 64 + xr;
    const int boff = (wn * 64  + fr) * 64 + xr;

    f32x4 acc[8][4];
    #pragma unroll
    for (int m = 0; m < 8; ++m)
        #pragma unroll
        for (int n = 0; n < 4; ++n)
            acc[m][n] = (f32x4){0.f, 0.f, 0.f, 0.f};

    s16x8 af0[8], bf0[4], af1[8], bf1[4];
    int kg = 0;

    // ---- prologue: stage chunks 0,1,2; gate 0,1; read frags(0) ----
    #pragma unroll
    for (int q = 0; q < 3; ++q) {
        gload_lds16(As0 + q * 32, lds + q * SLOTB + ldoff);
        gload_lds16(As1 + q * 32, lds + q * SLOTB +  8192 + ldoff);
        gload_lds16(Bs0 + q * 32, lds + q * SLOTB + 16384 + ldoff);
        gload_lds16(Bs1 + q * 32, lds + q * SLOTB + 24576 + ldoff);
    }
    kg = 3;
    asm volatile("s_waitcnt vmcnt(4)" ::: "memory");  // chunks 0,1 landed
    __builtin_amdgcn_s_barrier();                     // visible to all waves
    #pragma unroll
    for (int m = 0; m < 8; ++m)
        af0[m] = *(const s16x8*)(lds + aoff + m * 1024);
    #pragma unroll
    for (int n = 0; n < 4; ++n)
        bf0[n] = *(const s16x8*)(lds + 16384 + boff + n * 1024);

    #pragma unroll 1
    for (int it = 0; it < NCH / 4; ++it) {
        STEP(af0, bf0, af1, bf1, 1, 3);   // chunk 4it
        STEP(af1, bf1, af0, bf0, 2, 0);   // chunk 4it+1
        STEP(af0, bf0, af1, bf1, 3, 1);   // chunk 4it+2
        STEP(af1, bf1, af0, bf0, 0, 2);   // chunk 4it+3
    }
    asm volatile("s_waitcnt vmcnt(0) lgkmcnt(0)" ::: "memory");

    // ---- epilogue: C/D layout col = lane&15, row = (lane>>4)*4 + j ----
    const int ccol0 = bcol + wn * 64 + fr;
    const int crow0 = brow + wm * 128 + l16 * 4;
    float bv[4];
    #pragma unroll
    for (int n = 0; n < 4; ++n) bv[n] = bias[ccol0 + n * 16];

    #pragma unroll
    for (int m = 0; m < 8; ++m) {
        #pragma unroll
        for (int j = 0; j < 4; ++j) {
            float* Crow = C + (size_t)(crow0 + m * 16 + j) * NDIM;
            #pragma unroll
            for (int n = 0; n < 4; ++n)
                Crow[ccol0 + n * 16] = acc[m][n][j] + bv[n];
        }
    }
}

// ---------------- launcher ----------------

extern "C" void kernel_launch(void* const* d_in, const int* in_sizes, int n_in,
                              void* d_out, int out_size, void* d_ws, size_t ws_size,
                              hipStream_t stream) {
    const float* x        = (const float*)d_in[0];  // [4,4096,2048]
    const float* weights  = (const float*)d_in[1];  // [16]
    const float* W        = (const float*)d_in[2];  // [2048,2048]
    const float* b        = (const float*)d_in[3];  // [2048]
    const float* a_scales = (const float*)d_in[4];  // [2]
    const float* w_scales = (const float*)d_in[5];  // [2]
    float* out = (float*)d_out;

    __hip_bfloat16* xq = (__hip_bfloat16*)d_ws;                            // 67108864 B
    __hip_bfloat16* wq = (__hip_bfloat16*)((char*)d_ws + 67108864);        //  8388608 B
    float*          bm = (float*)((char*)d_ws + 67108864 + 8388608);       //     8192 B

    prep_w<<<dim3((NDIM * KDIM) / (256 * 8)), dim3(256), 0, stream>>>(W, weights, w_scales, wq);
    prep_b<<<dim3(NDIM / 256), dim3(256), 0, stream>>>(b, weights, bm);
    prep_x<<<dim3(((size_t)MDIM * KDIM) / (256 * 8)), dim3(256), 0, stream>>>(x, weights, a_scales, xq);
    gemm256<<<dim3((MDIM / BM) * (NDIM / BN)), dim3(512), 0, stream>>>(xq, wq, bm, out);
}